// Round 8
// baseline (445.784 us; speedup 1.0000x reference)
//
#include <hip/hip_runtime.h>
#include <hip/hip_cooperative_groups.h>
#include <math.h>

#define B_N 8
#define IN_N 8
#define J_N 8
#define S_N 187
#define F_N 64
#define O_N 64
#define C_N 67
#define KS_N 15
#define SF_N (S_N * F_N)   // 11968
#define E_N 256
#define ROWS_N (B_N * J_N * S_N)  // 11968
#define SQRT_SF 0.85467470f  // sqrt(187/256)

#define GRID_N 512          // primary coop grid: 2 blocks/CU x 256 CUs
#define NCOMB 376           // combined virtual blocks (47*8)
#define NKTQT 2992          // ktqt virtual blocks (11968/4)
#define NRAW 576            // raw virtual blocks (3*3*64)
#define NXPR 768            // xprime virtual blocks (12*64)
#define NFIN 384            // final virtual blocks (6*64)
#define SMEM_N 6976         // max floats over phases = 27904 B (<64KB: coop-occupancy safe)

typedef __attribute__((ext_vector_type(8))) _Float16 half8;
typedef __attribute__((ext_vector_type(4))) _Float16 half4;
typedef __attribute__((ext_vector_type(4))) float floatx4;

namespace cg = cooperative_groups;

// ---------------- wave helpers (wave = 64) ----------------
__device__ __forceinline__ float wave_sum(float v) {
#pragma unroll
  for (int off = 32; off > 0; off >>= 1) v += __shfl_down(v, off, 64);
  return __shfl(v, 0, 64);
}
__device__ __forceinline__ float wave_max(float v) {
#pragma unroll
  for (int off = 32; off > 0; off >>= 1) v = fmaxf(v, __shfl_down(v, off, 64));
  return __shfl(v, 0, 64);
}
__device__ __forceinline__ float lane_bc(float v, int l) {
  return __int_as_float(__builtin_amdgcn_readlane(__float_as_int(v), l));
}
__device__ __forceinline__ float bspline(float d) {
  float t2 = fmaxf(2.f - d, 0.f);
  float t1 = fmaxf(1.f - d, 0.f);
  return t2 * t2 * t2 * (1.f / 6.f) - t1 * t1 * t1 * (4.f / 6.f);
}
__device__ __forceinline__ float esumE(const float* __restrict__ esum_p, int bi, int j) {
  return (esum_p[bi * 32 + j] + esum_p[bi * 32 + 8 + j] +
          esum_p[bi * 32 + 16 + j] + esum_p[bi * 32 + 24 + j]) * (1.f / (float)SF_N);
}
__device__ __forceinline__ float get_inv095(const float* __restrict__ maxp, int nmaxp) {
  int lane = threadIdx.x & 63;
  float m = 0.f;
  for (int i = lane; i < nmaxp; i += 64) m = fmaxf(m, maxp[i]);
  return 0.95f / (wave_max(m) + 1e-8f);
}

// ================= phase device functions =================

// P1: per-block |x| maxima
__device__ void d_maxabs(const float4* __restrict__ x, float* __restrict__ maxp,
                         float* __restrict__ smem, int bid, int nblk) {
  const int n4 = (B_N * IN_N * S_N * F_N) / 4;
  int lane = threadIdx.x & 63, wid = threadIdx.x >> 6;
  float m = 0.f;
  for (int i = bid * 256 + threadIdx.x; i < n4; i += nblk * 256) {
    float4 v = x[i];
    m = fmaxf(m, fmaxf(fmaxf(fabsf(v.x), fabsf(v.y)), fmaxf(fabsf(v.z), fabsf(v.w))));
  }
  m = wave_max(m);
  if (lane == 0) smem[wid] = m;
  __syncthreads();
  if (threadIdx.x == 0)
    maxp[bid] = fmaxf(fmaxf(smem[0], smem[1]), fmaxf(smem[2], smem[3]));
}

// P2: energy partials for (bi, chunk)
__device__ void d_energy(const float* __restrict__ x_in, const float* __restrict__ sw,
                         const float* __restrict__ omiga, const float* __restrict__ maxp,
                         int nmaxp, float* __restrict__ esum_p, float* __restrict__ smem,
                         int bi, int chunk) {
  int i = bi & 7;
  float* wl = smem;          // 536
  float* aom = smem + 536;   // 8
  float* red = smem + 544;   // 32
  int lane = threadIdx.x & 63, wid = threadIdx.x >> 6;
  for (int idx = threadIdx.x; idx < J_N * C_N; idx += 256) wl[idx] = sw[i * J_N * C_N + idx];
  if (threadIdx.x < J_N) aom[threadIdx.x] = fabsf(omiga[i * J_N + threadIdx.x]);
  float inv095 = get_inv095(maxp, nmaxp);
  __syncthreads();
  float acc[J_N] = {0, 0, 0, 0, 0, 0, 0, 0};
  const float* xb = x_in + (long)bi * SF_N;
  int lo = chunk * 2992, hi = lo + 2992;
  for (int idx = lo + threadIdx.x; idx < hi; idx += 256) {
    float x = xb[idx];
    float xn = fminf(fmaxf(x * inv095, -0.99f), 0.99f);
    float u = (xn + 1.f) * 33.f;
    int c0 = (int)floorf(u) - 1;
    float sm[J_N] = {0, 0, 0, 0, 0, 0, 0, 0};
#pragma unroll
    for (int kk = 0; kk < 4; kk++) {
      int c = c0 + kk;
      if (c >= 0 && c < C_N) {
        float bas = bspline(fabsf(u - (float)c));
#pragma unroll
        for (int j = 0; j < J_N; j++) sm[j] += bas * wl[j * C_N + c];
      }
    }
#pragma unroll
    for (int j = 0; j < J_N; j++) {
      float a = sm[j] + aom[j] * x;
      acc[j] += a * a;
    }
  }
#pragma unroll
  for (int j = 0; j < J_N; j++) {
    float v = acc[j];
#pragma unroll
    for (int off = 32; off > 0; off >>= 1) v += __shfl_down(v, off, 64);
    if (lane == 0) red[wid * J_N + j] = v;
  }
  __syncthreads();
  if (threadIdx.x < J_N)
    esum_p[bi * 32 + chunk * 8 + threadIdx.x] =
        red[threadIdx.x] + red[8 + threadIdx.x] + red[16 + threadIdx.x] + red[24 + threadIdx.x];
}

// P3a: combined for virtual block vb = b*47 + tile
__device__ void d_comb(const float* __restrict__ x_in, const float* __restrict__ sw,
                       const float* __restrict__ omiga, const float* __restrict__ tau,
                       const float* __restrict__ temp, const float* __restrict__ maxp,
                       int nmaxp, const float* __restrict__ esum_p,
                       float* __restrict__ comb, float* __restrict__ smem, int vb) {
  int b = vb / 47, tile = vb - b * 47;
  float* wl = smem;           // 4288
  float* aom = smem + 4288;   // 64
  float* mk = smem + 4352;    // 64
  float tv = fabsf(temp[0]) * SQRT_SF + 1e-4f;
  for (int idx = threadIdx.x; idx < IN_N * J_N * C_N; idx += 256) wl[idx] = sw[idx];
  if (threadIdx.x < 64) {
    int i = threadIdx.x >> 3, j = threadIdx.x & 7;
    aom[threadIdx.x] = fabsf(omiga[threadIdx.x]);
    float E = esumE(esum_p, b * 8 + i, j);
    float sE = sqrtf(E + 1e-8f);
    float ta = fabsf(tau[threadIdx.x]);
    mk[threadIdx.x] = 1.f / (1.f + expf(-(sE - ta) / tv));
  }
  float inv095 = get_inv095(maxp, nmaxp);
  __syncthreads();
  int idx = tile * 256 + threadIdx.x;
  if (idx < SF_N) {
    float cb[J_N] = {0, 0, 0, 0, 0, 0, 0, 0};
    for (int i = 0; i < IN_N; i++) {
      float x = x_in[(b * IN_N + i) * SF_N + idx];
      float xn = fminf(fmaxf(x * inv095, -0.99f), 0.99f);
      float u = (xn + 1.f) * 33.f;
      int c0 = (int)floorf(u) - 1;
      float sm[J_N] = {0, 0, 0, 0, 0, 0, 0, 0};
#pragma unroll
      for (int kk = 0; kk < 4; kk++) {
        int c = c0 + kk;
        if (c >= 0 && c < C_N) {
          float bas = bspline(fabsf(u - (float)c));
#pragma unroll
          for (int j = 0; j < J_N; j++) sm[j] += bas * wl[(i * J_N + j) * C_N + c];
        }
      }
#pragma unroll
      for (int j = 0; j < J_N; j++) cb[j] += (sm[j] + aom[i * 8 + j] * x) * mk[i * 8 + j];
    }
#pragma unroll
    for (int j = 0; j < J_N; j++) comb[(b * J_N + j) * SF_N + idx] = cb[j];
  }
  __syncthreads();  // guard: block may run d_comb again (coop256) or reuse smem
}

// P3b: ktqt for virtual block vb (4 rows, one per wave); no LDS
__device__ void d_ktqt(const float* __restrict__ proj, const float* __restrict__ tau,
                       const float* __restrict__ temp, const float* __restrict__ esum_p,
                       _Float16* __restrict__ khi, _Float16* __restrict__ klo,
                       _Float16* __restrict__ qhi, _Float16* __restrict__ qlo, int vb) {
  int lane = threadIdx.x & 63, wid = threadIdx.x >> 6;
  int gr = vb * 4 + wid;  // 0..11967
  int bj = gr / S_N, s = gr - bj * S_N;
  int b = bj >> 3, j = bj & 7;
  int ig = lane >> 4;
  int f4 = (lane & 15) * 4;
  int iK = b * 8 + 2 * ig;
  int iQ = iK + 1;
  float tv = fabsf(temp[0]) * SQRT_SF + 1e-4f;
  float EK = esumE(esum_p, iK, j), EQ = esumE(esum_p, iQ, j);
  float sEK = sqrtf(EK + 1e-8f), sEQ = sqrtf(EQ + 1e-8f);
  float taK = fabsf(tau[(2 * ig) * 8 + j]), taQ = fabsf(tau[(2 * ig + 1) * 8 + j]);
  float gK = (sEK / (taK + 1e-8f)) / (1.f + expf(-(sEK - taK) / tv));
  float gQ = (sEQ / (taQ + 1e-8f)) / (1.f + expf(-(sEQ - taQ) / tv));
  float4 kr = *(const float4*)(proj + ((long)iK * S_N + s) * 64 + f4);
  float4 qr = *(const float4*)(proj + ((long)iQ * S_N + s) * 64 + f4);
  float kv[4] = {kr.x * gK, kr.y * gK, kr.z * gK, kr.w * gK};
  float qv[4] = {qr.x * gQ, qr.y * gQ, qr.z * gQ, qr.w * gQ};
  float mkv = wave_sum(kv[0] + kv[1] + kv[2] + kv[3]) * (1.f / 256.f);
  float mqv = wave_sum(qv[0] + qv[1] + qv[2] + qv[3]) * (1.f / 256.f);
  float vk = 0.f, vq = 0.f;
#pragma unroll
  for (int q = 0; q < 4; q++) {
    float dk = kv[q] - mkv; vk += dk * dk;
    float dq = qv[q] - mqv; vq += dq * dq;
  }
  vk = wave_sum(vk) * (1.f / 256.f);
  vq = wave_sum(vq) * (1.f / 256.f);
  float ik = 1.f / sqrtf(vk + 1e-5f);
  float iq = 1.f / sqrtf(vq + 1e-5f);
  long base = (long)gr * E_N + lane * 4;
  half4 hk4, lk4, hq4, lq4;
#pragma unroll
  for (int q = 0; q < 4; q++) {
    float fk = (kv[q] - mkv) * ik;
    float fq = (qv[q] - mqv) * iq;
    _Float16 hk = (_Float16)fk;
    _Float16 hq = (_Float16)fq;
    hk4[q] = hk; lk4[q] = (_Float16)(fk - (float)hk);
    hq4[q] = hq; lq4[q] = (_Float16)(fq - (float)hq);
  }
  *(half4*)(khi + base) = hk4;
  *(half4*)(klo + base) = lk4;
  *(half4*)(qhi + base) = hq4;
  *(half4*)(qlo + base) = lq4;
}

// P4a: raw QK^T via split-f16 MFMA; vb = st + 3*tt + 9*bj; no LDS
__device__ void d_raw(const _Float16* __restrict__ khi, const _Float16* __restrict__ klo,
                      const _Float16* __restrict__ qhi, const _Float16* __restrict__ qlo,
                      const float* __restrict__ temp, float* __restrict__ w1, int vb) {
  int st = vb % 3, tt = (vb / 3) % 3, bj = vb / 9;
  int lane = threadIdx.x & 63, wid = threadIdx.x >> 6;
  int quad = lane >> 4, m16 = lane & 15;
  int ebase = quad * 8;
  int mrow = st * 64 + wid * 16 + m16;
  if (mrow > S_N - 1) mrow = S_N - 1;
  long aoff = ((long)bj * S_N + mrow) * E_N + ebase;
  const _Float16* ah_p = khi + aoff;
  const _Float16* al_p = klo + aoff;
  const _Float16* bh_p[4];
  const _Float16* bl_p[4];
#pragma unroll
  for (int n = 0; n < 4; n++) {
    int t = tt * 64 + n * 16 + m16;
    if (t > S_N - 1) t = S_N - 1;
    long boff = ((long)bj * S_N + t) * E_N + ebase;
    bh_p[n] = qhi + boff;
    bl_p[n] = qlo + boff;
  }
  floatx4 acc[4] = {};
  for (int ec = 0; ec < 8; ec++) {
    half8 ah = *(const half8*)(ah_p + ec * 32);
    half8 al = *(const half8*)(al_p + ec * 32);
#pragma unroll
    for (int n = 0; n < 4; n++) {
      half8 bh = *(const half8*)(bh_p[n] + ec * 32);
      half8 bl = *(const half8*)(bl_p[n] + ec * 32);
      acc[n] = __builtin_amdgcn_mfma_f32_16x16x32_f16(ah, bh, acc[n], 0, 0, 0);
      acc[n] = __builtin_amdgcn_mfma_f32_16x16x32_f16(al, bh, acc[n], 0, 0, 0);
      acc[n] = __builtin_amdgcn_mfma_f32_16x16x32_f16(ah, bl, acc[n], 0, 0, 0);
    }
  }
  float tv = fabsf(temp[0]) * SQRT_SF + 1e-4f;
  float scale = 1.f / (16.f * tv);
#pragma unroll
  for (int n = 0; n < 4; n++) {
    int t = tt * 64 + n * 16 + m16;  // D col = lane&15
    if (t >= S_N) continue;
#pragma unroll
    for (int r = 0; r < 4; r++) {
      int s = st * 64 + wid * 16 + quad * 4 + r;  // D row = quad*4+reg
      if (s < S_N) w1[((long)bj * S_N + s) * S_N + t] = acc[n][r] * scale;
    }
  }
}

// P4b: xprime = LN(comb)*W2 + b; vb -> tile = vb%12, bj = vb/12
__device__ void d_xpr(const float* __restrict__ comb, const float* __restrict__ W2,
                      const float* __restrict__ bparam, const float* __restrict__ lns,
                      const float* __restrict__ lnb, float* __restrict__ xprime,
                      float* __restrict__ smem, int vb) {
  int tile = vb % 12, bj = vb / 12;
  int j = bj & 7;
  int lane = threadIdx.x & 63, wid = threadIdx.x >> 6;
  float* w2s = smem;            // 4096
  float* lss = smem + 4096;     // 64
  float* lbs = smem + 4160;     // 64
  __syncthreads();  // guard restage vs previous iteration's readers
  const float4* wg = (const float4*)(W2 + j * 4096);
  float4* ws4 = (float4*)w2s;
  for (int idx = threadIdx.x; idx < 1024; idx += 256) ws4[idx] = wg[idx];
  if (threadIdx.x < 64) {
    lss[threadIdx.x] = lns[j * 64 + threadIdx.x];
    lbs[threadIdx.x] = lnb[j * 64 + threadIdx.x];
  }
  __syncthreads();
  int sbase = tile * 16 + wid * 4;
  float xln[4], acc[4];
#pragma unroll
  for (int rr = 0; rr < 4; rr++) {
    int s = sbase + rr;
    int sc = (s < S_N) ? s : S_N - 1;
    float x = comb[((long)bj * S_N + sc) * 64 + lane];
    float m = wave_sum(x) * (1.f / 64.f);
    float d = x - m;
    float var = wave_sum(d * d) * (1.f / 64.f);
    xln[rr] = d / sqrtf(var + 1e-5f) * lss[lane] + lbs[lane];
    acc[rr] = bparam[(j * S_N + sc) * 64 + lane];
  }
#pragma unroll
  for (int h = 0; h < 64; h++) {
    float w2v = w2s[h * 64 + lane];
#pragma unroll
    for (int rr = 0; rr < 4; rr++) acc[rr] += lane_bc(xln[rr], h) * w2v;
  }
#pragma unroll
  for (int rr = 0; rr < 4; rr++) {
    int s = sbase + rr;
    if (s < S_N) xprime[((long)bj * S_N + s) * 64 + lane] = acc[rr];
  }
}

// P5: softmax + attn apply + conv + residuals; vb -> tile = vb%6, bj = vb/6
// w1 tile in LDS (24 KB); xp read from GLOBAL (coalesced, L1/L2-resident).
__device__ void d_final(const float* __restrict__ xprime, const float* __restrict__ w1,
                        const float* __restrict__ comb, const float* __restrict__ w3,
                        const float* __restrict__ alpha, const float* __restrict__ beta,
                        const float* __restrict__ theta, const float* __restrict__ gamma,
                        float* __restrict__ out, float* __restrict__ smem, int vb) {
  int tile = vb % 6, bj = vb / 6;
  int j = bj & 7;
  int lane = threadIdx.x & 63, wid = threadIdx.x >> 6;
  float* w1t = smem;          // 32*188 = 6016
  float* w3l = smem + 6016;   // 960
  __syncthreads();  // guard vs previous smem use
  int s0 = tile * 32;
  for (int idx = threadIdx.x; idx < 32 * S_N; idx += 256) {
    int r = idx / S_N, t = idx - r * S_N;
    int srow = s0 + r;
    w1t[r * 188 + t] = (srow < S_N) ? w1[((long)bj * S_N + srow) * S_N + t] : 0.f;
  }
  for (int idx = threadIdx.x; idx < 64 * KS_N; idx += 256) w3l[idx] = w3[j * 64 * KS_N + idx];
  __syncthreads();
  int o = lane;
  // in-LDS row softmax on this wave's 8 rows
#pragma unroll
  for (int rr = 0; rr < 8; rr++) {
    float* row = &w1t[(wid * 8 + rr) * 188];
    float v[3];
    float m = -1e30f;
#pragma unroll
    for (int q = 0; q < 3; q++) {
      int t = o + q * 64;
      v[q] = (t < S_N) ? row[t] : -1e30f;
      m = fmaxf(m, v[q]);
    }
    m = wave_max(m);
    float ssum = 0.f;
#pragma unroll
    for (int q = 0; q < 3; q++) {
      int t = o + q * 64;
      float e = (t < S_N) ? expf(v[q] - m) : 0.f;
      v[q] = e;
      ssum += e;
    }
    ssum = wave_sum(ssum);
    float invs = 1.f / ssum;
#pragma unroll
    for (int q = 0; q < 3; q++) {
      int t = o + q * 64;
      if (t < S_N) row[t] = v[q] * invs;
    }
  }
  const float* xpg = xprime + (long)bj * (S_N * 64);
  float aa = fabsf(alpha[j]), ba = fabsf(beta[j]), ta = fabsf(theta[j]), gv = gamma[j];
  float acc[8] = {0.f, 0.f, 0.f, 0.f, 0.f, 0.f, 0.f, 0.f};
  for (int t = 0; t < 184; t += 4) {
    float x0 = xpg[t * 64 + o];
    float x1 = xpg[(t + 1) * 64 + o];
    float x2 = xpg[(t + 2) * 64 + o];
    float x3 = xpg[(t + 3) * 64 + o];
#pragma unroll
    for (int rr = 0; rr < 8; rr++) {
      float4 wv = *(const float4*)&w1t[(wid * 8 + rr) * 188 + t];
      acc[rr] += wv.x * x0 + wv.y * x1 + wv.z * x2 + wv.w * x3;
    }
  }
#pragma unroll
  for (int t = 184; t < S_N; t++) {
    float xv = xpg[t * 64 + o];
#pragma unroll
    for (int rr = 0; rr < 8; rr++) acc[rr] += w1t[(wid * 8 + rr) * 188 + t] * xv;
  }
  float w3c[KS_N];
#pragma unroll
  for (int k = 0; k < KS_N; k++) w3c[k] = w3l[o * KS_N + k];
#pragma unroll
  for (int rr = 0; rr < 8; rr++) {
    int s = s0 + wid * 8 + rr;
    if (s >= S_N) continue;
    float conv = 0.f;
#pragma unroll
    for (int k = 0; k < KS_N; k++) {
      int si = s + k - 7;
      if (si >= 0 && si < S_N) conv += xpg[si * 64 + o] * w3c[k];
    }
    float res = ba * acc[rr] + aa * xpg[s * 64 + o] + ta * conv +
                gv * comb[((long)bj * S_N + s) * 64 + o];
    out[((long)bj * S_N + s) * 64 + o] = res;
  }
}

// ================= cooperative all-in-one =================
__global__ __launch_bounds__(256, 2) void k_all(
    const float* x_in, const float* proj, const float* sw, const float* tau,
    const float* temp, const float* omiga, const float* W2, const float* bparam,
    const float* lns, const float* lnb, const float* alpha, const float* beta,
    const float* theta, const float* gamma, const float* w3,
    float* out, float* xprime, float* maxp, float* esum_p,
    _Float16* khi, _Float16* klo, _Float16* qhi, _Float16* qlo,
    float* w1, float* comb, int nmaxp) {
  __shared__ __align__(16) float smem[SMEM_N];
  cg::grid_group grid = cg::this_grid();
  int G = gridDim.x;
  d_maxabs((const float4*)x_in, maxp, smem, blockIdx.x, G);
  grid.sync();
  if (blockIdx.x < 256)
    d_energy(x_in, sw, omiga, maxp, nmaxp, esum_p, smem, blockIdx.x >> 2, blockIdx.x & 3);
  grid.sync();
  for (int vb = blockIdx.x; vb < NCOMB + NKTQT; vb += G) {
    if (vb < NCOMB)
      d_comb(x_in, sw, omiga, tau, temp, maxp, nmaxp, esum_p, comb, smem, vb);
    else
      d_ktqt(proj, tau, temp, esum_p, khi, klo, qhi, qlo, vb - NCOMB);
  }
  grid.sync();
  for (int vb = blockIdx.x; vb < NRAW + NXPR; vb += G) {
    if (vb < NRAW)
      d_raw(khi, klo, qhi, qlo, temp, w1, vb);
    else
      d_xpr(comb, W2, bparam, lns, lnb, xprime, smem, vb - NRAW);
  }
  grid.sync();
  for (int vb = blockIdx.x; vb < NFIN; vb += G)
    d_final(xprime, w1, comb, w3, alpha, beta, theta, gamma, out, smem, vb);
}

// ================= fallback wrappers (regular launches) =================
__global__ __launch_bounds__(256, 2) void k_f1(const float4* x, float* maxp) {
  __shared__ __align__(16) float smem[4];
  d_maxabs(x, maxp, smem, blockIdx.x, gridDim.x);
}
__global__ __launch_bounds__(256, 2) void k_f2(const float* x_in, const float* sw,
                                               const float* omiga, const float* maxp,
                                               int nmaxp, float* esum_p) {
  __shared__ __align__(16) float smem[576];
  d_energy(x_in, sw, omiga, maxp, nmaxp, esum_p, smem, blockIdx.x >> 2, blockIdx.x & 3);
}
__global__ __launch_bounds__(256, 2) void k_f3(const float* x_in, const float* sw,
                                               const float* omiga, const float* tau,
                                               const float* temp, const float* maxp, int nmaxp,
                                               const float* esum_p, const float* proj,
                                               float* comb, _Float16* khi, _Float16* klo,
                                               _Float16* qhi, _Float16* qlo) {
  __shared__ __align__(16) float smem[4416];
  if (blockIdx.x < NCOMB)
    d_comb(x_in, sw, omiga, tau, temp, maxp, nmaxp, esum_p, comb, smem, blockIdx.x);
  else
    d_ktqt(proj, tau, temp, esum_p, khi, klo, qhi, qlo, blockIdx.x - NCOMB);
}
__global__ __launch_bounds__(256, 2) void k_f4(const _Float16* khi, const _Float16* klo,
                                               const _Float16* qhi, const _Float16* qlo,
                                               const float* temp, float* w1, const float* comb,
                                               const float* W2, const float* bparam,
                                               const float* lns, const float* lnb,
                                               float* xprime) {
  __shared__ __align__(16) float smem[4224];
  if (blockIdx.x < NRAW)
    d_raw(khi, klo, qhi, qlo, temp, w1, blockIdx.x);
  else
    d_xpr(comb, W2, bparam, lns, lnb, xprime, smem, blockIdx.x - NRAW);
}
__global__ __launch_bounds__(256, 2) void k_f5(const float* xprime, const float* w1,
                                               const float* comb, const float* w3,
                                               const float* alpha, const float* beta,
                                               const float* theta, const float* gamma,
                                               float* out) {
  __shared__ __align__(16) float smem[SMEM_N];
  d_final(xprime, w1, comb, w3, alpha, beta, theta, gamma, out, smem, blockIdx.x);
}

extern "C" void kernel_launch(void* const* d_in, const int* in_sizes, int n_in,
                              void* d_out, int out_size, void* d_ws, size_t ws_size,
                              hipStream_t stream) {
  const float* x_in   = (const float*)d_in[0];
  const float* proj   = (const float*)d_in[1];
  const float* sw     = (const float*)d_in[2];
  const float* tau    = (const float*)d_in[3];
  const float* temp   = (const float*)d_in[4];
  const float* omiga  = (const float*)d_in[5];
  const float* W2     = (const float*)d_in[6];
  const float* bparam = (const float*)d_in[7];
  const float* lns    = (const float*)d_in[8];
  const float* lnb    = (const float*)d_in[9];
  const float* alpha  = (const float*)d_in[10];
  const float* beta   = (const float*)d_in[11];
  const float* theta  = (const float*)d_in[12];
  const float* gamma  = (const float*)d_in[13];
  const float* w3     = (const float*)d_in[14];

  float* out = (float*)d_out;
  float* xprime = out + B_N * J_N * S_N * O_N;  // second output, written directly

  float* wsf = (float*)d_ws;
  float* maxp   = wsf;                            // up to 512 floats (written by P1)
  float* esum_p = wsf + 512;                      // 2048 floats (written by P2)
  const long RE = (long)ROWS_N * E_N;             // 3,063,808 halves per array
  _Float16* khi = (_Float16*)(wsf + 4096);
  _Float16* klo = khi + RE;
  _Float16* qhi = klo + RE;
  _Float16* qlo = qhi + RE;
  float* w1   = wsf + 4096 + 2 * RE;
  float* comb = w1 + (long)B_N * J_N * S_N * S_N;

  int nmaxp = GRID_N;
  void* kargs[] = {
      (void*)&x_in, (void*)&proj, (void*)&sw, (void*)&tau, (void*)&temp,
      (void*)&omiga, (void*)&W2, (void*)&bparam, (void*)&lns, (void*)&lnb,
      (void*)&alpha, (void*)&beta, (void*)&theta, (void*)&gamma, (void*)&w3,
      (void*)&out, (void*)&xprime, (void*)&maxp, (void*)&esum_p,
      (void*)&khi, (void*)&klo, (void*)&qhi, (void*)&qlo,
      (void*)&w1, (void*)&comb, (void*)&nmaxp};
  hipError_t e = hipLaunchCooperativeKernel((void*)k_all, dim3(GRID_N), dim3(256),
                                            kargs, 0, stream);
  if (e != hipSuccess) {
    (void)hipGetLastError();
    nmaxp = 256;  // retry at 1 block/CU co-residency
    e = hipLaunchCooperativeKernel((void*)k_all, dim3(256), dim3(256), kargs, 0, stream);
  }
  if (e != hipSuccess) {
    (void)hipGetLastError();
    // regular-launch fallback (round-6 semantics)
    int nm = 512;
    k_f1<<<512, 256, 0, stream>>>((const float4*)x_in, maxp);
    k_f2<<<256, 256, 0, stream>>>(x_in, sw, omiga, maxp, nm, esum_p);
    k_f3<<<NCOMB + NKTQT, 256, 0, stream>>>(x_in, sw, omiga, tau, temp, maxp, nm,
                                            esum_p, proj, comb, khi, klo, qhi, qlo);
    k_f4<<<NRAW + NXPR, 256, 0, stream>>>(khi, klo, qhi, qlo, temp, w1, comb, W2,
                                          bparam, lns, lnb, xprime);
    k_f5<<<NFIN, 256, 0, stream>>>(xprime, w1, comb, w3, alpha, beta, theta, gamma, out);
  }
}

// Round 9
// 196.106 us; speedup vs baseline: 2.2732x; 2.2732x over previous
//
#include <hip/hip_runtime.h>
#include <math.h>

#define B_N 8
#define IN_N 8
#define J_N 8
#define S_N 187
#define F_N 64
#define O_N 64
#define C_N 67
#define KS_N 15
#define SF_N (S_N * F_N)   // 11968
#define E_N 256
#define ROWS_N (B_N * J_N * S_N)  // 11968
#define SQRT_SF 0.85467470f  // sqrt(187/256)

#define NCOMB 376           // combined blocks in k_mid (47*8)
#define NKTQT 2992          // ktqt blocks in k_mid (11968/4)
#define NRAW 576            // raw blocks in k_gemm (3*3*64)
#define NXPR 768            // xprime blocks in k_gemm (12*64)
#define NMAXP 256           // maxabs partial blocks

typedef __attribute__((ext_vector_type(8))) _Float16 half8;
typedef __attribute__((ext_vector_type(4))) _Float16 half4;
typedef __attribute__((ext_vector_type(4))) float floatx4;

// ---------------- wave helpers (wave = 64) ----------------
__device__ __forceinline__ float wave_sum(float v) {
#pragma unroll
  for (int off = 32; off > 0; off >>= 1) v += __shfl_down(v, off, 64);
  return __shfl(v, 0, 64);
}
__device__ __forceinline__ float wave_max(float v) {
#pragma unroll
  for (int off = 32; off > 0; off >>= 1) v = fmaxf(v, __shfl_down(v, off, 64));
  return __shfl(v, 0, 64);
}
__device__ __forceinline__ float lane_bc(float v, int l) {
  return __int_as_float(__builtin_amdgcn_readlane(__float_as_int(v), l));
}
__device__ __forceinline__ float bspline(float d) {
  float t2 = fmaxf(2.f - d, 0.f);
  float t1 = fmaxf(1.f - d, 0.f);
  return t2 * t2 * t2 * (1.f / 6.f) - t1 * t1 * t1 * (4.f / 6.f);
}
__device__ __forceinline__ float esumE(const float* __restrict__ esum_p, int bi, int j) {
  return (esum_p[bi * 32 + j] + esum_p[bi * 32 + 8 + j] +
          esum_p[bi * 32 + 16 + j] + esum_p[bi * 32 + 24 + j]) * (1.f / (float)SF_N);
}
__device__ __forceinline__ float get_inv095(const float* __restrict__ maxp) {
  int lane = threadIdx.x & 63;
  float m = 0.f;
#pragma unroll
  for (int k = 0; k < NMAXP / 64; k++) m = fmaxf(m, maxp[lane + k * 64]);
  return 0.95f / (wave_max(m) + 1e-8f);
}

// ---------------- D1. global max |x| -> per-block maxima ----------------
__global__ void k_maxabs(const float4* __restrict__ x, float* __restrict__ maxp, int n4) {
  __shared__ float red[4];
  int tid = blockIdx.x * 256 + threadIdx.x;
  float m = 0.f;
  for (int i = tid; i < n4; i += gridDim.x * 256) {
    float4 v = x[i];
    m = fmaxf(m, fmaxf(fmaxf(fabsf(v.x), fabsf(v.y)), fmaxf(fabsf(v.z), fabsf(v.w))));
  }
  m = wave_max(m);
  if ((threadIdx.x & 63) == 0) red[threadIdx.x >> 6] = m;
  __syncthreads();
  if (threadIdx.x == 0)
    maxp[blockIdx.x] = fmaxf(fmaxf(red[0], red[1]), fmaxf(red[2], red[3]));
}

// ---------------- D2. energy partials ----------------
// grid = 64*4 blocks: bi = blk>>2, chunk = blk&3; writes esum_p[bi][chunk][j]
__global__ void k_energy(const float* __restrict__ x_in, const float* __restrict__ sw,
                         const float* __restrict__ omiga, const float* __restrict__ maxp,
                         float* __restrict__ esum_p) {
  int bi = blockIdx.x >> 2, chunk = blockIdx.x & 3;
  int i = bi & 7;
  __shared__ float wl[J_N * C_N];
  __shared__ float aom[J_N];
  __shared__ float red[4 * J_N];
  for (int idx = threadIdx.x; idx < J_N * C_N; idx += 256) wl[idx] = sw[i * J_N * C_N + idx];
  if (threadIdx.x < J_N) aom[threadIdx.x] = fabsf(omiga[i * J_N + threadIdx.x]);
  int lane = threadIdx.x & 63, wid = threadIdx.x >> 6;
  float inv = get_inv095(maxp);
  __syncthreads();
  float acc[J_N] = {0, 0, 0, 0, 0, 0, 0, 0};
  const float* xb = x_in + (long)bi * SF_N;
  int lo = chunk * 2992, hi = lo + 2992;
  for (int idx = lo + threadIdx.x; idx < hi; idx += 256) {
    float x = xb[idx];
    float xn = fminf(fmaxf(x * inv, -0.99f), 0.99f);
    float u = (xn + 1.f) * 33.f;
    int c0 = (int)floorf(u) - 1;
    float sm[J_N] = {0, 0, 0, 0, 0, 0, 0, 0};
#pragma unroll
    for (int kk = 0; kk < 4; kk++) {
      int c = c0 + kk;
      if (c >= 0 && c < C_N) {
        float bas = bspline(fabsf(u - (float)c));
#pragma unroll
        for (int j = 0; j < J_N; j++) sm[j] += bas * wl[j * C_N + c];
      }
    }
#pragma unroll
    for (int j = 0; j < J_N; j++) {
      float a = sm[j] + aom[j] * x;
      acc[j] += a * a;
    }
  }
#pragma unroll
  for (int j = 0; j < J_N; j++) {
    float v = acc[j];
#pragma unroll
    for (int off = 32; off > 0; off >>= 1) v += __shfl_down(v, off, 64);
    if (lane == 0) red[wid * J_N + j] = v;
  }
  __syncthreads();
  if (threadIdx.x < J_N)
    esum_p[bi * 32 + chunk * 8 + threadIdx.x] =
        red[threadIdx.x] + red[8 + threadIdx.x] + red[16 + threadIdx.x] + red[24 + threadIdx.x];
}

// ---------------- D3. mid = combined U ktqt ----------------
__global__ void k_mid(const float* __restrict__ x_in, const float* __restrict__ sw,
                      const float* __restrict__ omiga, const float* __restrict__ tau,
                      const float* __restrict__ temp, const float* __restrict__ maxp,
                      const float* __restrict__ esum_p, const float* __restrict__ proj,
                      float* __restrict__ comb,
                      _Float16* __restrict__ khi, _Float16* __restrict__ klo,
                      _Float16* __restrict__ qhi, _Float16* __restrict__ qlo) {
  __shared__ float wl[IN_N * J_N * C_N];
  __shared__ float aom[IN_N * J_N];
  __shared__ float mk[IN_N * J_N];
  int lane = threadIdx.x & 63;
  float tv = fabsf(temp[0]) * SQRT_SF + 1e-4f;
  if (blockIdx.x < NCOMB) {
    // ---- combined: blk = b*47 + tile ----
    int b = blockIdx.x / 47, tile = blockIdx.x - b * 47;
    for (int idx = threadIdx.x; idx < IN_N * J_N * C_N; idx += 256) wl[idx] = sw[idx];
    if (threadIdx.x < 64) {
      int i = threadIdx.x >> 3, j = threadIdx.x & 7;
      aom[threadIdx.x] = fabsf(omiga[threadIdx.x]);
      float E = esumE(esum_p, b * 8 + i, j);
      float sE = sqrtf(E + 1e-8f);
      float ta = fabsf(tau[threadIdx.x]);
      mk[threadIdx.x] = 1.f / (1.f + expf(-(sE - ta) / tv));
    }
    float inv = get_inv095(maxp);
    __syncthreads();
    int idx = tile * 256 + threadIdx.x;
    if (idx < SF_N) {
      float cb[J_N] = {0, 0, 0, 0, 0, 0, 0, 0};
      for (int i = 0; i < IN_N; i++) {
        float x = x_in[(b * IN_N + i) * SF_N + idx];
        float xn = fminf(fmaxf(x * inv, -0.99f), 0.99f);
        float u = (xn + 1.f) * 33.f;
        int c0 = (int)floorf(u) - 1;
        float sm[J_N] = {0, 0, 0, 0, 0, 0, 0, 0};
#pragma unroll
        for (int kk = 0; kk < 4; kk++) {
          int c = c0 + kk;
          if (c >= 0 && c < C_N) {
            float bas = bspline(fabsf(u - (float)c));
#pragma unroll
            for (int j = 0; j < J_N; j++) sm[j] += bas * wl[(i * J_N + j) * C_N + c];
          }
        }
#pragma unroll
        for (int j = 0; j < J_N; j++) cb[j] += (sm[j] + aom[i * 8 + j] * x) * mk[i * 8 + j];
      }
#pragma unroll
      for (int j = 0; j < J_N; j++) comb[(b * J_N + j) * SF_N + idx] = cb[j];
    }
  } else {
    // ---- ktqt: one wave per (b,j,s) row; g computed inline ----
    int w = threadIdx.x >> 6;
    int gr = (blockIdx.x - NCOMB) * 4 + w;  // 0..11967
    int bj = gr / S_N, s = gr - bj * S_N;
    int b = bj >> 3, j = bj & 7;
    int ig = lane >> 4;           // i-group 0..3
    int f4 = (lane & 15) * 4;     // f base
    int iK = b * 8 + 2 * ig;
    int iQ = iK + 1;
    float EK = esumE(esum_p, iK, j), EQ = esumE(esum_p, iQ, j);
    float sEK = sqrtf(EK + 1e-8f), sEQ = sqrtf(EQ + 1e-8f);
    float taK = fabsf(tau[(2 * ig) * 8 + j]), taQ = fabsf(tau[(2 * ig + 1) * 8 + j]);
    float gK = (sEK / (taK + 1e-8f)) / (1.f + expf(-(sEK - taK) / tv));
    float gQ = (sEQ / (taQ + 1e-8f)) / (1.f + expf(-(sEQ - taQ) / tv));
    float4 kr = *(const float4*)(proj + ((long)iK * S_N + s) * 64 + f4);
    float4 qr = *(const float4*)(proj + ((long)iQ * S_N + s) * 64 + f4);
    float kv[4] = {kr.x * gK, kr.y * gK, kr.z * gK, kr.w * gK};
    float qv[4] = {qr.x * gQ, qr.y * gQ, qr.z * gQ, qr.w * gQ};
    float mkv = wave_sum(kv[0] + kv[1] + kv[2] + kv[3]) * (1.f / 256.f);
    float mqv = wave_sum(qv[0] + qv[1] + qv[2] + qv[3]) * (1.f / 256.f);
    float vk = 0.f, vq = 0.f;
#pragma unroll
    for (int q = 0; q < 4; q++) {
      float dk = kv[q] - mkv; vk += dk * dk;
      float dq = qv[q] - mqv; vq += dq * dq;
    }
    vk = wave_sum(vk) * (1.f / 256.f);
    vq = wave_sum(vq) * (1.f / 256.f);
    float ik = 1.f / sqrtf(vk + 1e-5f);
    float iq = 1.f / sqrtf(vq + 1e-5f);
    long base = (long)gr * E_N + lane * 4;
    half4 hk4, lk4, hq4, lq4;
#pragma unroll
    for (int q = 0; q < 4; q++) {
      float fk = (kv[q] - mkv) * ik;
      float fq = (qv[q] - mqv) * iq;
      _Float16 hk = (_Float16)fk;
      _Float16 hq = (_Float16)fq;
      hk4[q] = hk; lk4[q] = (_Float16)(fk - (float)hk);
      hq4[q] = hq; lq4[q] = (_Float16)(fq - (float)hq);
    }
    *(half4*)(khi + base) = hk4;
    *(half4*)(klo + base) = lk4;
    *(half4*)(qhi + base) = hq4;
    *(half4*)(qlo + base) = lq4;
  }
}

// ---------------- D4. gemm = raw (MFMA) U xprime ----------------
__global__ void k_gemm(const _Float16* __restrict__ khi, const _Float16* __restrict__ klo,
                       const _Float16* __restrict__ qhi, const _Float16* __restrict__ qlo,
                       const float* __restrict__ temp, float* __restrict__ w1,
                       const float* __restrict__ comb, const float* __restrict__ W2,
                       const float* __restrict__ bparam, const float* __restrict__ lns,
                       const float* __restrict__ lnb, float* __restrict__ xprime) {
  __shared__ float smem[64 * 64 + 128];
  int lane = threadIdx.x & 63;
  if (blockIdx.x < NRAW) {
    // ---- raw: idx = st + 3*tt + 9*bj ----
    int idx = blockIdx.x;
    int st = idx % 3, tt = (idx / 3) % 3, bj = idx / 9;
    int wave = threadIdx.x >> 6;
    int quad = lane >> 4, m16 = lane & 15;
    int ebase = quad * 8;
    int mrow = st * 64 + wave * 16 + m16;
    if (mrow > S_N - 1) mrow = S_N - 1;
    long aoff = ((long)bj * S_N + mrow) * E_N + ebase;
    const _Float16* ah_p = khi + aoff;
    const _Float16* al_p = klo + aoff;
    const _Float16* bh_p[4];
    const _Float16* bl_p[4];
#pragma unroll
    for (int n = 0; n < 4; n++) {
      int t = tt * 64 + n * 16 + m16;
      if (t > S_N - 1) t = S_N - 1;
      long boff = ((long)bj * S_N + t) * E_N + ebase;
      bh_p[n] = qhi + boff;
      bl_p[n] = qlo + boff;
    }
    floatx4 acc[4] = {};
    for (int ec = 0; ec < 8; ec++) {
      half8 ah = *(const half8*)(ah_p + ec * 32);
      half8 al = *(const half8*)(al_p + ec * 32);
#pragma unroll
      for (int n = 0; n < 4; n++) {
        half8 bh = *(const half8*)(bh_p[n] + ec * 32);
        half8 bl = *(const half8*)(bl_p[n] + ec * 32);
        acc[n] = __builtin_amdgcn_mfma_f32_16x16x32_f16(ah, bh, acc[n], 0, 0, 0);
        acc[n] = __builtin_amdgcn_mfma_f32_16x16x32_f16(al, bh, acc[n], 0, 0, 0);
        acc[n] = __builtin_amdgcn_mfma_f32_16x16x32_f16(ah, bl, acc[n], 0, 0, 0);
      }
    }
    float tv = fabsf(temp[0]) * SQRT_SF + 1e-4f;
    float scale = 1.f / (16.f * tv);
#pragma unroll
    for (int n = 0; n < 4; n++) {
      int t = tt * 64 + n * 16 + m16;  // D col = lane&15
      if (t >= S_N) continue;
#pragma unroll
      for (int r = 0; r < 4; r++) {
        int s = st * 64 + wave * 16 + quad * 4 + r;  // D row = quad*4+reg
        if (s < S_N) w1[((long)bj * S_N + s) * S_N + t] = acc[n][r] * scale;
      }
    }
  } else {
    // ---- xprime: q = blk-576: tile = q%12, bj = q/12 ----
    int q = blockIdx.x - NRAW;
    int tile = q % 12, bj = q / 12;
    int j = bj & 7;
    float* w2s = smem;
    float* lss = smem + 4096;
    float* lbs = smem + 4160;
    const float4* wg = (const float4*)(W2 + j * 4096);
    float4* ws4 = (float4*)w2s;
    for (int idx = threadIdx.x; idx < 1024; idx += 256) ws4[idx] = wg[idx];
    if (threadIdx.x < 64) {
      lss[threadIdx.x] = lns[j * 64 + threadIdx.x];
      lbs[threadIdx.x] = lnb[j * 64 + threadIdx.x];
    }
    __syncthreads();
    int w = threadIdx.x >> 6;
    int sbase = tile * 16 + w * 4;
    float xln[4], acc[4];
#pragma unroll
    for (int rr = 0; rr < 4; rr++) {
      int s = sbase + rr;
      int sc = (s < S_N) ? s : S_N - 1;
      float x = comb[((long)bj * S_N + sc) * 64 + lane];
      float m = wave_sum(x) * (1.f / 64.f);
      float d = x - m;
      float var = wave_sum(d * d) * (1.f / 64.f);
      xln[rr] = d / sqrtf(var + 1e-5f) * lss[lane] + lbs[lane];
      acc[rr] = bparam[(j * S_N + sc) * 64 + lane];
    }
#pragma unroll
    for (int h = 0; h < 64; h++) {
      float w2v = w2s[h * 64 + lane];
#pragma unroll
      for (int rr = 0; rr < 4; rr++) acc[rr] += lane_bc(xln[rr], h) * w2v;
    }
#pragma unroll
    for (int rr = 0; rr < 4; rr++) {
      int s = sbase + rr;
      if (s < S_N) xprime[((long)bj * S_N + s) * 64 + lane] = acc[rr];
    }
  }
}

// ---------------- D5. final: softmax + attn apply + conv + residuals --------
// grid (6 s-tiles of 32, 64 bj), 256 thr; wave w owns rows w*8..w*8+7.
__global__ void k_final(const float* __restrict__ xprime, const float* __restrict__ w1,
                        const float* __restrict__ comb, const float* __restrict__ w3,
                        const float* __restrict__ alpha, const float* __restrict__ beta,
                        const float* __restrict__ theta, const float* __restrict__ gamma,
                        float* __restrict__ out) {
  int tile = blockIdx.x, bj = blockIdx.y;
  int j = bj & 7;
  __shared__ float xp[S_N * 64];     // 47872 B
  __shared__ float w1t[32 * 188];    // 24064 B
  __shared__ float w3l[64 * KS_N];   // 3840 B  -> total 75776 B, 2 blocks/CU
  const float4* xpg4 = (const float4*)(xprime + (long)bj * (S_N * 64));
  float4* xp4 = (float4*)xp;
  for (int idx = threadIdx.x; idx < S_N * 16; idx += 256) xp4[idx] = xpg4[idx];
  int s0 = tile * 32;
  for (int idx = threadIdx.x; idx < 32 * S_N; idx += 256) {
    int r = idx / S_N, t = idx - r * S_N;
    int srow = s0 + r;
    w1t[r * 188 + t] = (srow < S_N) ? w1[((long)bj * S_N + srow) * S_N + t] : 0.f;
  }
  for (int idx = threadIdx.x; idx < 64 * KS_N; idx += 256) w3l[idx] = w3[j * 64 * KS_N + idx];
  __syncthreads();
  int w = threadIdx.x >> 6, o = threadIdx.x & 63;
  // in-LDS row softmax on this wave's 8 rows (rows w*8.. consumed only by wave w)
#pragma unroll
  for (int rr = 0; rr < 8; rr++) {
    float* row = &w1t[(w * 8 + rr) * 188];
    float v[3];
    float m = -1e30f;
#pragma unroll
    for (int q = 0; q < 3; q++) {
      int t = o + q * 64;
      v[q] = (t < S_N) ? row[t] : -1e30f;
      m = fmaxf(m, v[q]);
    }
    m = wave_max(m);
    float ssum = 0.f;
#pragma unroll
    for (int q = 0; q < 3; q++) {
      int t = o + q * 64;
      float e = (t < S_N) ? expf(v[q] - m) : 0.f;
      v[q] = e;
      ssum += e;
    }
    ssum = wave_sum(ssum);
    float invs = 1.f / ssum;
#pragma unroll
    for (int q = 0; q < 3; q++) {
      int t = o + q * 64;
      if (t < S_N) row[t] = v[q] * invs;
    }
  }
  // conv taps hoisted to registers (15 LDS reads/lane instead of 120)
  float w3c[KS_N];
#pragma unroll
  for (int k = 0; k < KS_N; k++) w3c[k] = w3l[o * KS_N + k];
  float aa = fabsf(alpha[j]), ba = fabsf(beta[j]), ta = fabsf(theta[j]), gv = gamma[j];
  float acc[8] = {0.f, 0.f, 0.f, 0.f, 0.f, 0.f, 0.f, 0.f};
  for (int t = 0; t < 184; t += 4) {
    float x0 = xp[t * 64 + o];
    float x1 = xp[(t + 1) * 64 + o];
    float x2 = xp[(t + 2) * 64 + o];
    float x3 = xp[(t + 3) * 64 + o];
#pragma unroll
    for (int rr = 0; rr < 8; rr++) {
      float4 wv = *(const float4*)&w1t[(w * 8 + rr) * 188 + t];
      acc[rr] += wv.x * x0 + wv.y * x1 + wv.z * x2 + wv.w * x3;
    }
  }
#pragma unroll
  for (int t = 184; t < S_N; t++) {
    float xv = xp[t * 64 + o];
#pragma unroll
    for (int rr = 0; rr < 8; rr++) acc[rr] += w1t[(w * 8 + rr) * 188 + t] * xv;
  }
#pragma unroll
  for (int rr = 0; rr < 8; rr++) {
    int s = s0 + w * 8 + rr;
    if (s >= S_N) continue;
    float conv = 0.f;
#pragma unroll
    for (int k = 0; k < KS_N; k++) {
      int si = s + k - 7;
      if (si >= 0 && si < S_N) conv += xp[si * 64 + o] * w3c[k];
    }
    float res = ba * acc[rr] + aa * xp[s * 64 + o] + ta * conv +
                gv * comb[((long)bj * S_N + s) * 64 + o];
    out[((long)bj * S_N + s) * 64 + o] = res;
  }
}

extern "C" void kernel_launch(void* const* d_in, const int* in_sizes, int n_in,
                              void* d_out, int out_size, void* d_ws, size_t ws_size,
                              hipStream_t stream) {
  const float* x_in   = (const float*)d_in[0];
  const float* proj   = (const float*)d_in[1];
  const float* sw     = (const float*)d_in[2];
  const float* tau    = (const float*)d_in[3];
  const float* temp   = (const float*)d_in[4];
  const float* omiga  = (const float*)d_in[5];
  const float* W2     = (const float*)d_in[6];
  const float* bparam = (const float*)d_in[7];
  const float* lns    = (const float*)d_in[8];
  const float* lnb    = (const float*)d_in[9];
  const float* alpha  = (const float*)d_in[10];
  const float* beta   = (const float*)d_in[11];
  const float* theta  = (const float*)d_in[12];
  const float* gamma  = (const float*)d_in[13];
  const float* w3     = (const float*)d_in[14];

  float* out = (float*)d_out;
  float* xprime = out + B_N * J_N * S_N * O_N;  // second output, written directly

  float* wsf = (float*)d_ws;
  float* maxp   = wsf;                            // 256 floats (all written by D1)
  float* esum_p = wsf + 512;                      // 2048 floats (all written by D2)
  const long RE = (long)ROWS_N * E_N;             // 3,063,808 halves per array
  _Float16* khi = (_Float16*)(wsf + 4096);
  _Float16* klo = khi + RE;
  _Float16* qhi = klo + RE;
  _Float16* qlo = qhi + RE;
  float* w1   = wsf + 4096 + 2 * RE;
  float* comb = w1 + (long)B_N * J_N * S_N * S_N;

  // 5 regular dispatches (round-6 structure, best known: coop mega-fusion
  // regressed 197->344 us from the 2-blocks/CU occupancy cap — reverted)
  k_maxabs<<<NMAXP, 256, 0, stream>>>((const float4*)x_in, maxp, (B_N * IN_N * S_N * F_N) / 4);
  k_energy<<<256, 256, 0, stream>>>(x_in, sw, omiga, maxp, esum_p);
  k_mid<<<NCOMB + NKTQT, 256, 0, stream>>>(x_in, sw, omiga, tau, temp, maxp, esum_p,
                                           proj, comb, khi, klo, qhi, qlo);
  k_gemm<<<NRAW + NXPR, 256, 0, stream>>>(khi, klo, qhi, qlo, temp, w1,
                                          comb, W2, bparam, lns, lnb, xprime);
  k_final<<<dim3(6, 64), 256, 0, stream>>>(xprime, w1, comb, w3, alpha, beta, theta, gamma, out);
}

// Round 10
// 183.086 us; speedup vs baseline: 2.4348x; 1.0711x over previous
//
#include <hip/hip_runtime.h>
#include <math.h>

#define B_N 8
#define IN_N 8
#define J_N 8
#define S_N 187
#define F_N 64
#define O_N 64
#define C_N 67
#define KS_N 15
#define SF_N (S_N * F_N)   // 11968
#define E_N 256
#define ROWS_N (B_N * J_N * S_N)  // 11968
#define SQRT_SF 0.85467470f  // sqrt(187/256)

#define NCOMB 376           // combined blocks in k_mid (47*8)
#define NKTQT 2992          // ktqt blocks in k_mid (11968/4)
#define NRAW 576            // raw blocks in k_gemm (3*3*64)
#define NXPR 768            // xprime blocks in k_gemm (12*64)
#define NMAXP 256           // maxabs partial blocks

typedef __attribute__((ext_vector_type(8))) _Float16 half8;
typedef __attribute__((ext_vector_type(4))) _Float16 half4;
typedef __attribute__((ext_vector_type(4))) float floatx4;

// ---------------- wave helpers (wave = 64) ----------------
__device__ __forceinline__ float wave_sum(float v) {
#pragma unroll
  for (int off = 32; off > 0; off >>= 1) v += __shfl_down(v, off, 64);
  return __shfl(v, 0, 64);
}
__device__ __forceinline__ float wave_max(float v) {
#pragma unroll
  for (int off = 32; off > 0; off >>= 1) v = fmaxf(v, __shfl_down(v, off, 64));
  return __shfl(v, 0, 64);
}
__device__ __forceinline__ float lane_bc(float v, int l) {
  return __int_as_float(__builtin_amdgcn_readlane(__float_as_int(v), l));
}
__device__ __forceinline__ float bspline(float d) {
  float t2 = fmaxf(2.f - d, 0.f);
  float t1 = fmaxf(1.f - d, 0.f);
  return t2 * t2 * t2 * (1.f / 6.f) - t1 * t1 * t1 * (4.f / 6.f);
}
__device__ __forceinline__ float esumE(const float* __restrict__ esum_p, int bi, int j) {
  return (esum_p[bi * 32 + j] + esum_p[bi * 32 + 8 + j] +
          esum_p[bi * 32 + 16 + j] + esum_p[bi * 32 + 24 + j]) * (1.f / (float)SF_N);
}
__device__ __forceinline__ float get_inv095(const float* __restrict__ maxp) {
  int lane = threadIdx.x & 63;
  float m = 0.f;
#pragma unroll
  for (int k = 0; k < NMAXP / 64; k++) m = fmaxf(m, maxp[lane + k * 64]);
  return 0.95f / (wave_max(m) + 1e-8f);
}

// ---------------- D1. global max |x| -> per-block maxima ----------------
__global__ void k_maxabs(const float4* __restrict__ x, float* __restrict__ maxp, int n4) {
  __shared__ float red[4];
  int tid = blockIdx.x * 256 + threadIdx.x;
  float m = 0.f;
  for (int i = tid; i < n4; i += gridDim.x * 256) {
    float4 v = x[i];
    m = fmaxf(m, fmaxf(fmaxf(fabsf(v.x), fabsf(v.y)), fmaxf(fabsf(v.z), fabsf(v.w))));
  }
  m = wave_max(m);
  if ((threadIdx.x & 63) == 0) red[threadIdx.x >> 6] = m;
  __syncthreads();
  if (threadIdx.x == 0)
    maxp[blockIdx.x] = fmaxf(fmaxf(red[0], red[1]), fmaxf(red[2], red[3]));
}

// ---------------- D2. energy partials ----------------
__global__ void k_energy(const float* __restrict__ x_in, const float* __restrict__ sw,
                         const float* __restrict__ omiga, const float* __restrict__ maxp,
                         float* __restrict__ esum_p) {
  int bi = blockIdx.x >> 2, chunk = blockIdx.x & 3;
  int i = bi & 7;
  __shared__ float wl[J_N * C_N];
  __shared__ float aom[J_N];
  __shared__ float red[4 * J_N];
  for (int idx = threadIdx.x; idx < J_N * C_N; idx += 256) wl[idx] = sw[i * J_N * C_N + idx];
  if (threadIdx.x < J_N) aom[threadIdx.x] = fabsf(omiga[i * J_N + threadIdx.x]);
  int lane = threadIdx.x & 63, wid = threadIdx.x >> 6;
  float inv = get_inv095(maxp);
  __syncthreads();
  float acc[J_N] = {0, 0, 0, 0, 0, 0, 0, 0};
  const float* xb = x_in + (long)bi * SF_N;
  int lo = chunk * 2992, hi = lo + 2992;
  for (int idx = lo + threadIdx.x; idx < hi; idx += 256) {
    float x = xb[idx];
    float xn = fminf(fmaxf(x * inv, -0.99f), 0.99f);
    float u = (xn + 1.f) * 33.f;
    int c0 = (int)floorf(u) - 1;
    float sm[J_N] = {0, 0, 0, 0, 0, 0, 0, 0};
#pragma unroll
    for (int kk = 0; kk < 4; kk++) {
      int c = c0 + kk;
      if (c >= 0 && c < C_N) {
        float bas = bspline(fabsf(u - (float)c));
#pragma unroll
        for (int j = 0; j < J_N; j++) sm[j] += bas * wl[j * C_N + c];
      }
    }
#pragma unroll
    for (int j = 0; j < J_N; j++) {
      float a = sm[j] + aom[j] * x;
      acc[j] += a * a;
    }
  }
#pragma unroll
  for (int j = 0; j < J_N; j++) {
    float v = acc[j];
#pragma unroll
    for (int off = 32; off > 0; off >>= 1) v += __shfl_down(v, off, 64);
    if (lane == 0) red[wid * J_N + j] = v;
  }
  __syncthreads();
  if (threadIdx.x < J_N)
    esum_p[bi * 32 + chunk * 8 + threadIdx.x] =
        red[threadIdx.x] + red[8 + threadIdx.x] + red[16 + threadIdx.x] + red[24 + threadIdx.x];
}

// ---------------- D3. mid = combined U ktqt ----------------
__global__ void k_mid(const float* __restrict__ x_in, const float* __restrict__ sw,
                      const float* __restrict__ omiga, const float* __restrict__ tau,
                      const float* __restrict__ temp, const float* __restrict__ maxp,
                      const float* __restrict__ esum_p, const float* __restrict__ proj,
                      float* __restrict__ comb,
                      _Float16* __restrict__ khi, _Float16* __restrict__ klo,
                      _Float16* __restrict__ qhi, _Float16* __restrict__ qlo) {
  __shared__ float wl[IN_N * J_N * C_N];
  __shared__ float aom[IN_N * J_N];
  __shared__ float mk[IN_N * J_N];
  int lane = threadIdx.x & 63;
  float tv = fabsf(temp[0]) * SQRT_SF + 1e-4f;
  if (blockIdx.x < NCOMB) {
    // ---- combined: blk = b*47 + tile ----
    int b = blockIdx.x / 47, tile = blockIdx.x - b * 47;
    for (int idx = threadIdx.x; idx < IN_N * J_N * C_N; idx += 256) wl[idx] = sw[idx];
    if (threadIdx.x < 64) {
      int i = threadIdx.x >> 3, j = threadIdx.x & 7;
      aom[threadIdx.x] = fabsf(omiga[threadIdx.x]);
      float E = esumE(esum_p, b * 8 + i, j);
      float sE = sqrtf(E + 1e-8f);
      float ta = fabsf(tau[threadIdx.x]);
      mk[threadIdx.x] = 1.f / (1.f + expf(-(sE - ta) / tv));
    }
    float inv = get_inv095(maxp);
    __syncthreads();
    int idx = tile * 256 + threadIdx.x;
    if (idx < SF_N) {
      float cb[J_N] = {0, 0, 0, 0, 0, 0, 0, 0};
      for (int i = 0; i < IN_N; i++) {
        float x = x_in[(b * IN_N + i) * SF_N + idx];
        float xn = fminf(fmaxf(x * inv, -0.99f), 0.99f);
        float u = (xn + 1.f) * 33.f;
        int c0 = (int)floorf(u) - 1;
        float sm[J_N] = {0, 0, 0, 0, 0, 0, 0, 0};
#pragma unroll
        for (int kk = 0; kk < 4; kk++) {
          int c = c0 + kk;
          if (c >= 0 && c < C_N) {
            float bas = bspline(fabsf(u - (float)c));
#pragma unroll
            for (int j = 0; j < J_N; j++) sm[j] += bas * wl[(i * J_N + j) * C_N + c];
          }
        }
#pragma unroll
        for (int j = 0; j < J_N; j++) cb[j] += (sm[j] + aom[i * 8 + j] * x) * mk[i * 8 + j];
      }
#pragma unroll
      for (int j = 0; j < J_N; j++) comb[(b * J_N + j) * SF_N + idx] = cb[j];
    }
  } else {
    // ---- ktqt: one wave per (b,j,s) row; g computed inline ----
    int w = threadIdx.x >> 6;
    int gr = (blockIdx.x - NCOMB) * 4 + w;  // 0..11967
    int bj = gr / S_N, s = gr - bj * S_N;
    int b = bj >> 3, j = bj & 7;
    int ig = lane >> 4;           // i-group 0..3
    int f4 = (lane & 15) * 4;     // f base
    int iK = b * 8 + 2 * ig;
    int iQ = iK + 1;
    float EK = esumE(esum_p, iK, j), EQ = esumE(esum_p, iQ, j);
    float sEK = sqrtf(EK + 1e-8f), sEQ = sqrtf(EQ + 1e-8f);
    float taK = fabsf(tau[(2 * ig) * 8 + j]), taQ = fabsf(tau[(2 * ig + 1) * 8 + j]);
    float gK = (sEK / (taK + 1e-8f)) / (1.f + expf(-(sEK - taK) / tv));
    float gQ = (sEQ / (taQ + 1e-8f)) / (1.f + expf(-(sEQ - taQ) / tv));
    float4 kr = *(const float4*)(proj + ((long)iK * S_N + s) * 64 + f4);
    float4 qr = *(const float4*)(proj + ((long)iQ * S_N + s) * 64 + f4);
    float kv[4] = {kr.x * gK, kr.y * gK, kr.z * gK, kr.w * gK};
    float qv[4] = {qr.x * gQ, qr.y * gQ, qr.z * gQ, qr.w * gQ};
    float mkv = wave_sum(kv[0] + kv[1] + kv[2] + kv[3]) * (1.f / 256.f);
    float mqv = wave_sum(qv[0] + qv[1] + qv[2] + qv[3]) * (1.f / 256.f);
    float vk = 0.f, vq = 0.f;
#pragma unroll
    for (int q = 0; q < 4; q++) {
      float dk = kv[q] - mkv; vk += dk * dk;
      float dq = qv[q] - mqv; vq += dq * dq;
    }
    vk = wave_sum(vk) * (1.f / 256.f);
    vq = wave_sum(vq) * (1.f / 256.f);
    float ik = 1.f / sqrtf(vk + 1e-5f);
    float iq = 1.f / sqrtf(vq + 1e-5f);
    long base = (long)gr * E_N + lane * 4;
    half4 hk4, lk4, hq4, lq4;
#pragma unroll
    for (int q = 0; q < 4; q++) {
      float fk = (kv[q] - mkv) * ik;
      float fq = (qv[q] - mqv) * iq;
      _Float16 hk = (_Float16)fk;
      _Float16 hq = (_Float16)fq;
      hk4[q] = hk; lk4[q] = (_Float16)(fk - (float)hk);
      hq4[q] = hq; lq4[q] = (_Float16)(fq - (float)hq);
    }
    *(half4*)(khi + base) = hk4;
    *(half4*)(klo + base) = lk4;
    *(half4*)(qhi + base) = hq4;
    *(half4*)(qlo + base) = lq4;
  }
}

// ---------------- D4. gemm = raw (MFMA) U xprime ----------------
__global__ void k_gemm(const _Float16* __restrict__ khi, const _Float16* __restrict__ klo,
                       const _Float16* __restrict__ qhi, const _Float16* __restrict__ qlo,
                       const float* __restrict__ temp, float* __restrict__ w1,
                       const float* __restrict__ comb, const float* __restrict__ W2,
                       const float* __restrict__ bparam, const float* __restrict__ lns,
                       const float* __restrict__ lnb, float* __restrict__ xprime) {
  __shared__ float smem[64 * 64 + 128];
  int lane = threadIdx.x & 63;
  if (blockIdx.x < NRAW) {
    // ---- raw: idx = st + 3*tt + 9*bj ----
    int idx = blockIdx.x;
    int st = idx % 3, tt = (idx / 3) % 3, bj = idx / 9;
    int wave = threadIdx.x >> 6;
    int quad = lane >> 4, m16 = lane & 15;
    int ebase = quad * 8;
    int mrow = st * 64 + wave * 16 + m16;
    if (mrow > S_N - 1) mrow = S_N - 1;
    long aoff = ((long)bj * S_N + mrow) * E_N + ebase;
    const _Float16* ah_p = khi + aoff;
    const _Float16* al_p = klo + aoff;
    const _Float16* bh_p[4];
    const _Float16* bl_p[4];
#pragma unroll
    for (int n = 0; n < 4; n++) {
      int t = tt * 64 + n * 16 + m16;
      if (t > S_N - 1) t = S_N - 1;
      long boff = ((long)bj * S_N + t) * E_N + ebase;
      bh_p[n] = qhi + boff;
      bl_p[n] = qlo + boff;
    }
    floatx4 acc[4] = {};
    for (int ec = 0; ec < 8; ec++) {
      half8 ah = *(const half8*)(ah_p + ec * 32);
      half8 al = *(const half8*)(al_p + ec * 32);
#pragma unroll
      for (int n = 0; n < 4; n++) {
        half8 bh = *(const half8*)(bh_p[n] + ec * 32);
        half8 bl = *(const half8*)(bl_p[n] + ec * 32);
        acc[n] = __builtin_amdgcn_mfma_f32_16x16x32_f16(ah, bh, acc[n], 0, 0, 0);
        acc[n] = __builtin_amdgcn_mfma_f32_16x16x32_f16(al, bh, acc[n], 0, 0, 0);
        acc[n] = __builtin_amdgcn_mfma_f32_16x16x32_f16(ah, bl, acc[n], 0, 0, 0);
      }
    }
    float tv = fabsf(temp[0]) * SQRT_SF + 1e-4f;
    float scale = 1.f / (16.f * tv);
#pragma unroll
    for (int n = 0; n < 4; n++) {
      int t = tt * 64 + n * 16 + m16;  // D col = lane&15
      if (t >= S_N) continue;
#pragma unroll
      for (int r = 0; r < 4; r++) {
        int s = st * 64 + wave * 16 + quad * 4 + r;  // D row = quad*4+reg
        if (s < S_N) w1[((long)bj * S_N + s) * S_N + t] = acc[n][r] * scale;
      }
    }
  } else {
    // ---- xprime: q = blk-576: tile = q%12, bj = q/12 ----
    int q = blockIdx.x - NRAW;
    int tile = q % 12, bj = q / 12;
    int j = bj & 7;
    float* w2s = smem;
    float* lss = smem + 4096;
    float* lbs = smem + 4160;
    const float4* wg = (const float4*)(W2 + j * 4096);
    float4* ws4 = (float4*)w2s;
    for (int idx = threadIdx.x; idx < 1024; idx += 256) ws4[idx] = wg[idx];
    if (threadIdx.x < 64) {
      lss[threadIdx.x] = lns[j * 64 + threadIdx.x];
      lbs[threadIdx.x] = lnb[j * 64 + threadIdx.x];
    }
    __syncthreads();
    int w = threadIdx.x >> 6;
    int sbase = tile * 16 + w * 4;
    float xln[4], acc[4];
#pragma unroll
    for (int rr = 0; rr < 4; rr++) {
      int s = sbase + rr;
      int sc = (s < S_N) ? s : S_N - 1;
      float x = comb[((long)bj * S_N + sc) * 64 + lane];
      float m = wave_sum(x) * (1.f / 64.f);
      float d = x - m;
      float var = wave_sum(d * d) * (1.f / 64.f);
      xln[rr] = d / sqrtf(var + 1e-5f) * lss[lane] + lbs[lane];
      acc[rr] = bparam[(j * S_N + sc) * 64 + lane];
    }
#pragma unroll
    for (int h = 0; h < 64; h++) {
      float w2v = w2s[h * 64 + lane];
#pragma unroll
      for (int rr = 0; rr < 4; rr++) acc[rr] += lane_bc(xln[rr], h) * w2v;
    }
#pragma unroll
    for (int rr = 0; rr < 4; rr++) {
      int s = sbase + rr;
      if (s < S_N) xprime[((long)bj * S_N + s) * 64 + lane] = acc[rr];
    }
  }
}

// ---------------- D5. final: softmax + attn apply + conv + residuals --------
// grid (12 s-tiles of 16, 64 bj), 256 thr; wave w owns rows w*4..w*4+3.
// LDS holds ONLY the w1 tile (12 KB -> 3 blocks/CU co-resident, 12 waves/CU);
// xp and w3 stream from global (coalesced / L1-shared). Was: xp in LDS ->
// 75.8 KB block, 2 blocks/CU cap, 15% occupancy, 58 us (latency-starved).
__global__ void k_final(const float* __restrict__ xprime, const float* __restrict__ w1,
                        const float* __restrict__ comb, const float* __restrict__ w3,
                        const float* __restrict__ alpha, const float* __restrict__ beta,
                        const float* __restrict__ theta, const float* __restrict__ gamma,
                        float* __restrict__ out) {
  int tile = blockIdx.x, bj = blockIdx.y;
  int j = bj & 7;
  __shared__ float w1t[16 * 188];    // 12032 B total LDS
  int s0 = tile * 16;
  for (int idx = threadIdx.x; idx < 16 * S_N; idx += 256) {
    int r = idx / S_N, t = idx - r * S_N;
    int srow = s0 + r;
    w1t[r * 188 + t] = (srow < S_N) ? w1[((long)bj * S_N + srow) * S_N + t] : 0.f;
  }
  __syncthreads();
  int w = threadIdx.x >> 6, o = threadIdx.x & 63;
  // in-LDS row softmax on this wave's 4 rows (consumed only by wave w)
#pragma unroll
  for (int rr = 0; rr < 4; rr++) {
    float* row = &w1t[(w * 4 + rr) * 188];
    float v[3];
    float m = -1e30f;
#pragma unroll
    for (int q = 0; q < 3; q++) {
      int t = o + q * 64;
      v[q] = (t < S_N) ? row[t] : -1e30f;
      m = fmaxf(m, v[q]);
    }
    m = wave_max(m);
    float ssum = 0.f;
#pragma unroll
    for (int q = 0; q < 3; q++) {
      int t = o + q * 64;
      float e = (t < S_N) ? expf(v[q] - m) : 0.f;
      v[q] = e;
      ssum += e;
    }
    ssum = wave_sum(ssum);
    float invs = 1.f / ssum;
#pragma unroll
    for (int q = 0; q < 3; q++) {
      int t = o + q * 64;
      if (t < S_N) row[t] = v[q] * invs;
    }
  }
  // conv taps straight from global (L1-resident: same j across the block)
  float w3c[KS_N];
#pragma unroll
  for (int k = 0; k < KS_N; k++) w3c[k] = w3[j * 64 * KS_N + o * KS_N + k];
  const float* xpg = xprime + (long)bj * (S_N * 64);
  float aa = fabsf(alpha[j]), ba = fabsf(beta[j]), ta = fabsf(theta[j]), gv = gamma[j];
  float acc[4] = {0.f, 0.f, 0.f, 0.f};
  for (int t = 0; t < 184; t += 4) {
    float x0 = xpg[t * 64 + o];
    float x1 = xpg[(t + 1) * 64 + o];
    float x2 = xpg[(t + 2) * 64 + o];
    float x3 = xpg[(t + 3) * 64 + o];
#pragma unroll
    for (int rr = 0; rr < 4; rr++) {
      float4 wv = *(const float4*)&w1t[(w * 4 + rr) * 188 + t];
      acc[rr] += wv.x * x0 + wv.y * x1 + wv.z * x2 + wv.w * x3;
    }
  }
#pragma unroll
  for (int t = 184; t < S_N; t++) {
    float xv = xpg[t * 64 + o];
#pragma unroll
    for (int rr = 0; rr < 4; rr++) acc[rr] += w1t[(w * 4 + rr) * 188 + t] * xv;
  }
#pragma unroll
  for (int rr = 0; rr < 4; rr++) {
    int s = s0 + w * 4 + rr;
    if (s >= S_N) continue;
    float conv = 0.f;
#pragma unroll
    for (int k = 0; k < KS_N; k++) {
      int si = s + k - 7;
      if (si >= 0 && si < S_N) conv += xpg[si * 64 + o] * w3c[k];
    }
    float res = ba * acc[rr] + aa * xpg[s * 64 + o] + ta * conv +
                gv * comb[((long)bj * S_N + s) * 64 + o];
    out[((long)bj * S_N + s) * 64 + o] = res;
  }
}

extern "C" void kernel_launch(void* const* d_in, const int* in_sizes, int n_in,
                              void* d_out, int out_size, void* d_ws, size_t ws_size,
                              hipStream_t stream) {
  const float* x_in   = (const float*)d_in[0];
  const float* proj   = (const float*)d_in[1];
  const float* sw     = (const float*)d_in[2];
  const float* tau    = (const float*)d_in[3];
  const float* temp   = (const float*)d_in[4];
  const float* omiga  = (const float*)d_in[5];
  const float* W2     = (const float*)d_in[6];
  const float* bparam = (const float*)d_in[7];
  const float* lns    = (const float*)d_in[8];
  const float* lnb    = (const float*)d_in[9];
  const float* alpha  = (const float*)d_in[10];
  const float* beta   = (const float*)d_in[11];
  const float* theta  = (const float*)d_in[12];
  const float* gamma  = (const float*)d_in[13];
  const float* w3     = (const float*)d_in[14];

  float* out = (float*)d_out;
  float* xprime = out + B_N * J_N * S_N * O_N;  // second output, written directly

  float* wsf = (float*)d_ws;
  float* maxp   = wsf;                            // 256 floats (all written by D1)
  float* esum_p = wsf + 512;                      // 2048 floats (all written by D2)
  const long RE = (long)ROWS_N * E_N;             // 3,063,808 halves per array
  _Float16* khi = (_Float16*)(wsf + 4096);
  _Float16* klo = khi + RE;
  _Float16* qhi = klo + RE;
  _Float16* qlo = qhi + RE;
  float* w1   = wsf + 4096 + 2 * RE;
  float* comb = w1 + (long)B_N * J_N * S_N * S_N;

  k_maxabs<<<NMAXP, 256, 0, stream>>>((const float4*)x_in, maxp, (B_N * IN_N * S_N * F_N) / 4);
  k_energy<<<256, 256, 0, stream>>>(x_in, sw, omiga, maxp, esum_p);
  k_mid<<<NCOMB + NKTQT, 256, 0, stream>>>(x_in, sw, omiga, tau, temp, maxp, esum_p,
                                           proj, comb, khi, klo, qhi, qlo);
  k_gemm<<<NRAW + NXPR, 256, 0, stream>>>(khi, klo, qhi, qlo, temp, w1,
                                          comb, W2, bparam, lns, lnb, xprime);
  k_final<<<dim3(12, 64), 256, 0, stream>>>(xprime, w1, comb, w3, alpha, beta, theta, gamma, out);
}